// Round 2
// baseline (13017.918 us; speedup 1.0000x reference)
//
#include <hip/hip_runtime.h>
#include <stdint.h>

// Autoregressive GRU  B=256, D=1024, T=128  — persistent cooperative kernel, v2.
// v1 post-mortem: VGPR_Count=60 + FETCH 2.7GB => weight/acc arrays spilled to
// scratch (array passed by pointer into lambda; 128-reg array vs allocator
// heuristics). v2 makes spills structurally impossible:
//   - 512 threads / 8 waves; wave = (gate q, k-half kh). Per-wave weights are
//     16 hi + 16 lo bf16x8 = 128 VGPRs, all NAMED variables (wh0..wh15,
//     wl0..wl15) -- no arrays, no address-taken, static everything.
//   - __launch_bounds__(512,2): 2 waves/SIMD, 256-VGPR cap (need ~200).
//   - LDS = only gbuf[4][64][16] (16 KB). k-half partial sums combined by
//     two-phase write/add in the epilogue (kh0 writes, kh1 adds).
//   - State h[t]: double-buffered bf16 hi+lo in ws (2 MB); f32 h_prev lives in
//     2 registers/thread. Per-rt-group 64-block barrier via agent-scope
//     atomics + threadfence (proven correct in v1).
//   - t=0: gates = [x@Uz | x@Ur | 0 | x@Uh]; stream U columns in f32 once,
//     split in-register; A = split(x). Same 3-term split-bf16 MFMA scheme.

#define DDIM    1024
#define THREE_D 3072
#define TSTEPS  128

typedef short bf16x8 __attribute__((ext_vector_type(8)));
typedef float f32x4  __attribute__((ext_vector_type(4)));

static __device__ __forceinline__ unsigned short f2bf(float f) {
    union { float f; uint32_t u; } v; v.f = f;
    uint32_t u = v.u;
    uint32_t r = u + 0x7FFFu + ((u >> 16) & 1u);   // round-to-nearest-even
    return (unsigned short)(r >> 16);
}
static __device__ __forceinline__ float bf2f(unsigned short h) {
    union { uint32_t u; float f; } v; v.u = ((uint32_t)h) << 16; return v.f;
}
static __device__ __forceinline__ void split8(const float* v, bf16x8& hi, bf16x8& lo) {
    #pragma unroll
    for (int j = 0; j < 8; ++j) {
        unsigned short h = f2bf(v[j]);
        hi[j] = (short)h;
        lo[j] = (short)f2bf(v[j] - bf2f(h));
    }
}

#define MFMA __builtin_amdgcn_mfma_f32_16x16x32_bf16

__global__ __launch_bounds__(512, 2) void gru_persistent(
    const float* __restrict__ x, const float* __restrict__ W,
    const float* __restrict__ U, const float* __restrict__ bias,
    float* __restrict__ out, unsigned short* __restrict__ hb,
    int* __restrict__ syncc)
{
    __shared__ float gbuf[4][64][16];   // 16 KB

    const int tid  = threadIdx.x;
    const int lane = tid & 63;
    const int wid  = tid >> 6;          // 0..7
    const int q    = wid >> 1;          // gate quarter (z | r | Wh | Uh)
    const int kh   = wid & 1;           // k-half
    const int dt   = blockIdx.x & 63;   // dim tile (16 dims)
    const int rt   = blockIdx.x >> 6;   // row tile (64 rows)
    const int llow = lane & 15;
    const int lhi  = lane >> 4;
    const int d    = dt * 16 + llow;    // B-frag column (dim within gate)
    const int kbase = kh * 16;          // this wave's first k-tile

    // ---- one-time fold: M = [Wz+Uz | Wr+Ur | Wh | Uh], split bf16 hi+lo,
    //      ALL in named registers (wave reads back only what it folded) ----
    bf16x8 wh0,wh1,wh2,wh3,wh4,wh5,wh6,wh7,wh8,wh9,wh10,wh11,wh12,wh13,wh14,wh15;
    bf16x8 wl0,wl1,wl2,wl3,wl4,wl5,wl6,wl7,wl8,wl9,wl10,wl11,wl12,wl13,wl14,wl15;
    {
        const int cc = (q == 0) ? d : (q == 1) ? (1024 + d) : (2048 + d);
        const float* m1 = (q == 3) ? U : W;
        const int k0 = kbase * 32 + lhi * 8;
        #define FOLD(KT) { float v[8]; \
            _Pragma("unroll") for (int j = 0; j < 8; ++j) { \
                int k = k0 + KT * 32 + j; \
                float val = m1[(size_t)k * THREE_D + cc]; \
                if (q <= 1) val += U[(size_t)k * THREE_D + cc]; \
                v[j] = val; } \
            split8(v, wh##KT, wl##KT); }
        FOLD(0) FOLD(1) FOLD(2) FOLD(3) FOLD(4) FOLD(5) FOLD(6) FOLD(7)
        FOLD(8) FOLD(9) FOLD(10) FOLD(11) FOLD(12) FOLD(13) FOLD(14) FOLD(15)
        #undef FOLD
    }

    // ---- epilogue constants: thread handles output rows erow, erow+32 ----
    const int erow = tid >> 4;          // 0..31
    const int ecol = tid & 15;
    const int dd   = dt * 16 + ecol;
    const float bz = bias[dd];
    const float br = bias[1024 + dd];
    const float bx = bias[2048 + dd];
    const size_t o0 = (size_t)(rt * 64 + erow) * (TSTEPS * DDIM) + dd;
    const size_t o1 = (size_t)(rt * 64 + erow + 32) * (TSTEPS * DDIM) + dd;
    const size_t h0 = (size_t)(rt * 64 + erow) * DDIM + dd;
    const size_t h1 = (size_t)(rt * 64 + erow + 32) * DDIM + dd;
    float hp0 = x[h0];
    float hp1 = x[h1];

    f32x4 acc0 = {0.f,0.f,0.f,0.f}, acc1 = acc0, acc2 = acc0, acc3 = acc0;

    // gbuf combine (two-phase: kh0 writes, kh1 adds) + gates + state stores.
    // C/D layout: col = lane&15, row = (lane>>4)*4 + reg  [measured m89]
    #define GW(ACC, M) { _Pragma("unroll") for (int r = 0; r < 4; ++r) \
        gbuf[q][(M) * 16 + lhi * 4 + r][llow] = (ACC)[r]; }
    #define GA(ACC, M) { _Pragma("unroll") for (int r = 0; r < 4; ++r) \
        gbuf[q][(M) * 16 + lhi * 4 + r][llow] += (ACC)[r]; }
    #define EPILOGUE(T, DH, DL) { \
        if (kh == 0) { GW(acc0,0) GW(acc1,1) GW(acc2,2) GW(acc3,3) } \
        __syncthreads(); \
        if (kh == 1) { GA(acc0,0) GA(acc1,1) GA(acc2,2) GA(acc3,3) } \
        __syncthreads(); \
        float gz0 = gbuf[0][erow][ecol] + bz; \
        float gr0 = gbuf[1][erow][ecol] + br; \
        float gx0 = gbuf[2][erow][ecol] + bx; \
        float gu0 = gbuf[3][erow][ecol]; \
        float gz1 = gbuf[0][erow+32][ecol] + bz; \
        float gr1 = gbuf[1][erow+32][ecol] + br; \
        float gx1 = gbuf[2][erow+32][ecol] + bx; \
        float gu1 = gbuf[3][erow+32][ecol]; \
        float z0 = 1.f/(1.f+__expf(-gz0)), z1 = 1.f/(1.f+__expf(-gz1)); \
        float r0 = 1.f/(1.f+__expf(-gr0)), r1 = 1.f/(1.f+__expf(-gr1)); \
        float hh0 = tanhf(gx0 + r0*gu0), hh1 = tanhf(gx1 + r1*gu1); \
        float hn0 = z0*hp0 + (1.f-z0)*hh0, hn1 = z1*hp1 + (1.f-z1)*hh1; \
        hp0 = hn0; hp1 = hn1; \
        out[o0 + (size_t)(T)*DDIM] = hn0; \
        out[o1 + (size_t)(T)*DDIM] = hn1; \
        { unsigned short hi_ = f2bf(hn0); (DH)[h0] = hi_; (DL)[h0] = f2bf(hn0 - bf2f(hi_)); } \
        { unsigned short hi_ = f2bf(hn1); (DH)[h1] = hi_; (DL)[h1] = f2bf(hn1 - bf2f(hi_)); } }

    // 64-block barrier per rt-group; per-(rt,t) counter, 64 B apart (proven v1)
    auto barrier = [&](int t) {
        __threadfence();                 // release: drain state stores to L2+
        __syncthreads();
        if (tid == 0) {
            int* c = syncc + (t * 4 + rt) * 16;
            __hip_atomic_fetch_add(c, 1, __ATOMIC_RELEASE, __HIP_MEMORY_SCOPE_AGENT);
            while (__hip_atomic_load(c, __ATOMIC_RELAXED, __HIP_MEMORY_SCOPE_AGENT) < 64)
                __builtin_amdgcn_s_sleep(2);
            __threadfence();             // acquire: invalidate stale L1/L2
        }
        __syncthreads();
    };

    __syncthreads();

    // ---- t = 0:  gates = [x@Uz | x@Ur | 0 | x@Uh], A = split(x) ----
    if (q != 2) {
        const float* xb = x + (size_t)(rt * 64 + llow) * DDIM + lhi * 8;
        const int cc = (q == 0) ? d : (q == 1) ? (1024 + d) : (2048 + d);
        const float* ub = U + cc;
        const int kg0 = kbase * 32;
        #define T0M(ACC, ROFF, KT) { float a[8]; bf16x8 ah, al; \
            _Pragma("unroll") for (int j = 0; j < 8; ++j) \
                a[j] = xb[(ROFF) * DDIM + kg0 + (KT) * 32 + j]; \
            split8(a, ah, al); \
            ACC = MFMA(ah, bh, ACC, 0,0,0); \
            ACC = MFMA(al, bh, ACC, 0,0,0); \
            ACC = MFMA(ah, bl, ACC, 0,0,0); }
        #define T0KT(KT) { bf16x8 bh, bl; \
            { float v[8]; \
              _Pragma("unroll") for (int j = 0; j < 8; ++j) \
                  v[j] = ub[(size_t)(kg0 + KT * 32 + lhi * 8 + j) * THREE_D]; \
              split8(v, bh, bl); } \
            T0M(acc0,  0, KT) T0M(acc1, 16, KT) T0M(acc2, 32, KT) T0M(acc3, 48, KT) }
        T0KT(0) T0KT(1) T0KT(2) T0KT(3) T0KT(4) T0KT(5) T0KT(6) T0KT(7)
        T0KT(8) T0KT(9) T0KT(10) T0KT(11) T0KT(12) T0KT(13) T0KT(14) T0KT(15)
        #undef T0KT
        #undef T0M
    }
    EPILOGUE(0, hb, hb + 262144)         // state[0] -> buf0
    barrier(0);

    // ---- t = 1 .. 127: B entirely in registers, A from state buffers ----
    for (int t = 1; t < TSTEPS; ++t) {
        const unsigned short* sh = hb + (size_t)((t - 1) & 1) * 524288;
        const unsigned short* sl = sh + 262144;
        unsigned short* dh = hb + (size_t)(t & 1) * 524288;
        unsigned short* dl = dh + 262144;
        const unsigned short* ahp = sh + (size_t)(rt * 64 + llow) * DDIM + lhi * 8 + kbase * 32;
        const unsigned short* alp = sl + (size_t)(rt * 64 + llow) * DDIM + lhi * 8 + kbase * 32;

        acc0 = f32x4{0.f,0.f,0.f,0.f}; acc1 = acc0; acc2 = acc0; acc3 = acc0;
        #define SM(ACC, ROFF, KT) { \
            bf16x8 ah = *(const bf16x8*)(ahp + (ROFF) * DDIM + (KT) * 32); \
            bf16x8 al = *(const bf16x8*)(alp + (ROFF) * DDIM + (KT) * 32); \
            ACC = MFMA(ah, wh##KT, ACC, 0,0,0); \
            ACC = MFMA(al, wh##KT, ACC, 0,0,0); \
            ACC = MFMA(ah, wl##KT, ACC, 0,0,0); }
        #define SKT(KT) { SM(acc0, 0, KT) SM(acc1, 16, KT) SM(acc2, 32, KT) SM(acc3, 48, KT) }
        SKT(0) SKT(1) SKT(2) SKT(3) SKT(4) SKT(5) SKT(6) SKT(7)
        SKT(8) SKT(9) SKT(10) SKT(11) SKT(12) SKT(13) SKT(14) SKT(15)
        #undef SKT
        #undef SM
        EPILOGUE(t, dh, dl)
        if (t < TSTEPS - 1) barrier(t);
    }
}

extern "C" void kernel_launch(void* const* d_in, const int* in_sizes, int n_in,
                              void* d_out, int out_size, void* d_ws, size_t ws_size,
                              hipStream_t stream) {
    const float* x = (const float*)d_in[0];
    const float* W = (const float*)d_in[1];
    const float* U = (const float*)d_in[2];
    const float* b = (const float*)d_in[3];
    float* out = (float*)d_out;

    // ws: 2 MB state (2 bufs x [hi 512KB | lo 512KB]) + 32 KB sync counters
    unsigned short* hb = (unsigned short*)d_ws;
    int* syncc = (int*)((char*)d_ws + (2u << 20));

    hipMemsetAsync(syncc, 0, 8192 * sizeof(int), stream);

    void* kargs[] = { (void*)&x, (void*)&W, (void*)&U, (void*)&b,
                      (void*)&out, (void*)&hb, (void*)&syncc };
    hipLaunchCooperativeKernel((const void*)gru_persistent, dim3(256), dim3(512),
                               kargs, 0, stream);
}

// Round 3
// 7789.116 us; speedup vs baseline: 1.6713x; 1.6713x over previous
//
#include <hip/hip_runtime.h>
#include <stdint.h>

// Autoregressive GRU  B=256, D=1024, T=128  — persistent cooperative kernel, v3.
// v2 post-mortem: per-step __threadfence() (device scope) = L2 writeback +
// L1/L2 invalidate on every CU every step -> every step's state reads came
// from HBM (FETCH 4.4 MB/step, BW*dur == bytes), ~100 us/step. Also VGPR=124
// => 128-reg named weight set STILL not resident.
// v3:
//  - State exchanged via RELAXED AGENT-SCOPE ATOMICS (sc0 sc1: bypass L1/L2,
//    read/write L3 coherent point). NO threadfence, NO bulk cache ops at all.
//    Barrier: asm s_waitcnt vmcnt(0) -> relaxed fetch_add -> relaxed spin.
//  - Weights-hi (128 KB) in LDS as wave-private store (ds_read_b128/ktile);
//    weights-lo = 16 named bf16x8 per wave (64 VGPRs). 8 waves = (q, kh).
//  - gbuf padded [4][64][17] (v2 had 12.6M LDS bank conflicts on the 4-way
//    write aliasing). Epilogue: thread owns 1 row x 2 adjacent cols so each
//    state store is one u32 atomic (hi-pair / lo-pair).
//  - Same proven pieces: 3-term split-bf16 MFMA, per-rt 64-block barrier,
//    double-buffered state, f32 h_prev in regs, t=0 = [x@Uz | x@Ur | 0 | x@Uh].

#define DDIM    1024
#define THREE_D 3072
#define TSTEPS  128

typedef short bf16x8 __attribute__((ext_vector_type(8)));
typedef float f32x4  __attribute__((ext_vector_type(4)));

union frag_u { unsigned long long d[2]; bf16x8 v; };

static __device__ __forceinline__ unsigned short f2bf(float f) {
    union { float f; uint32_t u; } v; v.f = f;
    uint32_t u = v.u;
    uint32_t r = u + 0x7FFFu + ((u >> 16) & 1u);   // round-to-nearest-even
    return (unsigned short)(r >> 16);
}
static __device__ __forceinline__ float bf2f(unsigned short h) {
    union { uint32_t u; float f; } v; v.u = ((uint32_t)h) << 16; return v.f;
}
static __device__ __forceinline__ void split8(const float* v, bf16x8& hi, bf16x8& lo) {
    #pragma unroll
    for (int j = 0; j < 8; ++j) {
        unsigned short h = f2bf(v[j]);
        hi[j] = (short)h;
        lo[j] = (short)f2bf(v[j] - bf2f(h));
    }
}

#define MFMA __builtin_amdgcn_mfma_f32_16x16x32_bf16
#define ALOAD(P)    __hip_atomic_load((P), __ATOMIC_RELAXED, __HIP_MEMORY_SCOPE_AGENT)
#define ASTORE(P,V) __hip_atomic_store((P), (V), __ATOMIC_RELAXED, __HIP_MEMORY_SCOPE_AGENT)

__global__ __launch_bounds__(512, 2) void gru_persistent(
    const float* __restrict__ x, const float* __restrict__ W,
    const float* __restrict__ U, const float* __restrict__ bias,
    float* __restrict__ out, unsigned short* __restrict__ hb,
    int* __restrict__ syncc)
{
    extern __shared__ char smem[];
    unsigned short* whi = (unsigned short*)smem;   // [4][32][64][8] shorts = 128 KB
    float* gbuf = (float*)(smem + 131072);         // [4][64][17] f32 = 17408 B

    const int tid  = threadIdx.x;
    const int lane = tid & 63;
    const int wid  = tid >> 6;          // 0..7
    const int q    = wid >> 1;          // gate quarter (z | r | Wh | Uh)
    const int kh   = wid & 1;           // k-half
    const int dt   = blockIdx.x & 63;   // dim tile (16 dims)
    const int rt   = blockIdx.x >> 6;   // row tile (64 rows)
    const int llow = lane & 15;
    const int lhi  = lane >> 4;
    const int d    = dt * 16 + llow;    // B-frag column (dim within gate)
    const int kbase = kh * 16;          // first k-tile of this wave

    unsigned short* whibase = whi + (((q * 32 + kbase) * 64 + lane) << 3);

    // ---- one-time fold: M = [Wz+Uz | Wr+Ur | Wh | Uh]; hi -> LDS, lo -> regs
    bf16x8 wl0,wl1,wl2,wl3,wl4,wl5,wl6,wl7,wl8,wl9,wl10,wl11,wl12,wl13,wl14,wl15;
    {
        const int cc = (q == 0) ? d : (q == 1) ? (1024 + d) : (2048 + d);
        const float* m1 = (q == 3) ? U : W;
        const int k0 = kbase * 32 + lhi * 8;
        #define FOLD(KT) { float v[8]; bf16x8 bh_; \
            _Pragma("unroll") for (int j = 0; j < 8; ++j) { \
                int k = k0 + KT * 32 + j; \
                float val = m1[(size_t)k * THREE_D + cc]; \
                if (q <= 1) val += U[(size_t)k * THREE_D + cc]; \
                v[j] = val; } \
            split8(v, bh_, wl##KT); \
            *(bf16x8*)(whibase + KT * 512) = bh_; }
        FOLD(0) FOLD(1) FOLD(2) FOLD(3) FOLD(4) FOLD(5) FOLD(6) FOLD(7)
        FOLD(8) FOLD(9) FOLD(10) FOLD(11) FOLD(12) FOLD(13) FOLD(14) FOLD(15)
        #undef FOLD
    }

    // ---- epilogue constants: thread owns 1 row x 2 adjacent cols ----
    const int erow = tid >> 3;          // 0..63
    const int ec   = (tid & 7) * 2;     // 0,2,...,14
    const int dd   = dt * 16 + ec;
    const float bz0 = bias[dd],        bz1 = bias[dd + 1];
    const float br0 = bias[1024 + dd], br1 = bias[1025 + dd];
    const float bx0 = bias[2048 + dd], bx1 = bias[2049 + dd];
    const int grow = rt * 64 + erow;
    const size_t obase = (size_t)grow * (TSTEPS * DDIM) + dd;
    const int sidx  = (grow * DDIM + dd) >> 1;     // u32 index into state
    float hp0 = x[(size_t)grow * DDIM + dd];
    float hp1 = x[(size_t)grow * DDIM + dd + 1];

    f32x4 acc0 = {0.f,0.f,0.f,0.f}, acc1 = acc0, acc2 = acc0, acc3 = acc0;

    // MFMA C/D: col = lane&15, row = (lane>>4)*4 + reg  [measured m89]
    #define GW(ACC, M) { _Pragma("unroll") for (int r = 0; r < 4; ++r) \
        gbuf[(q * 64 + (M) * 16 + lhi * 4 + r) * 17 + llow] = (ACC)[r]; }
    #define GA(ACC, M) { _Pragma("unroll") for (int r = 0; r < 4; ++r) \
        gbuf[(q * 64 + (M) * 16 + lhi * 4 + r) * 17 + llow] += (ACC)[r]; }
    #define EPILOGUE(T, DHI, DLO) { \
        if (kh == 0) { GW(acc0,0) GW(acc1,1) GW(acc2,2) GW(acc3,3) } \
        __syncthreads(); \
        if (kh == 1) { GA(acc0,0) GA(acc1,1) GA(acc2,2) GA(acc3,3) } \
        __syncthreads(); \
        float gz0 = gbuf[(0*64 + erow)*17 + ec]     + bz0; \
        float gz1 = gbuf[(0*64 + erow)*17 + ec + 1] + bz1; \
        float gr0 = gbuf[(1*64 + erow)*17 + ec]     + br0; \
        float gr1 = gbuf[(1*64 + erow)*17 + ec + 1] + br1; \
        float gx0 = gbuf[(2*64 + erow)*17 + ec]     + bx0; \
        float gx1 = gbuf[(2*64 + erow)*17 + ec + 1] + bx1; \
        float gu0 = gbuf[(3*64 + erow)*17 + ec]; \
        float gu1 = gbuf[(3*64 + erow)*17 + ec + 1]; \
        float z0 = 1.f/(1.f+__expf(-gz0)), z1 = 1.f/(1.f+__expf(-gz1)); \
        float r0 = 1.f/(1.f+__expf(-gr0)), r1 = 1.f/(1.f+__expf(-gr1)); \
        float hh0 = tanhf(gx0 + r0*gu0), hh1 = tanhf(gx1 + r1*gu1); \
        float hn0 = z0*hp0 + (1.f-z0)*hh0, hn1 = z1*hp1 + (1.f-z1)*hh1; \
        hp0 = hn0; hp1 = hn1; \
        out[obase + (size_t)(T)*DDIM]     = hn0; \
        out[obase + (size_t)(T)*DDIM + 1] = hn1; \
        unsigned short h0_ = f2bf(hn0), h1_ = f2bf(hn1); \
        unsigned int hw_ = (unsigned int)h0_ | ((unsigned int)h1_ << 16); \
        unsigned int lw_ = (unsigned int)f2bf(hn0 - bf2f(h0_)) \
                         | ((unsigned int)f2bf(hn1 - bf2f(h1_)) << 16); \
        ASTORE((DHI) + sidx, hw_); \
        ASTORE((DLO) + sidx, lw_); }

    // per-rt-group 64-block barrier; state ops are agent-scope so no fences
    #define BARRIER(T) { \
        asm volatile("s_waitcnt vmcnt(0)" ::: "memory"); \
        __syncthreads(); \
        if (tid == 0) { \
            int* c = syncc + ((T) * 4 + rt) * 16; \
            __hip_atomic_fetch_add(c, 1, __ATOMIC_RELAXED, __HIP_MEMORY_SCOPE_AGENT); \
            while (__hip_atomic_load(c, __ATOMIC_RELAXED, __HIP_MEMORY_SCOPE_AGENT) < 64) \
                __builtin_amdgcn_s_sleep(4); \
        } \
        __syncthreads(); }

    __syncthreads();

    // ---- t = 0:  gates = [x@Uz | x@Ur | 0 | x@Uh], A = split(x) ----
    if (q != 2) {
        const float* xb = x + (size_t)(rt * 64 + llow) * DDIM + lhi * 8;
        const int cc = (q == 0) ? d : (q == 1) ? (1024 + d) : (2048 + d);
        const float* ub = U + cc;
        const int kg0 = kbase * 32;
        #define T0M(ACC, ROFF, KT) { float a[8]; bf16x8 ah, al; \
            _Pragma("unroll") for (int j = 0; j < 8; ++j) \
                a[j] = xb[(ROFF) * DDIM + kg0 + (KT) * 32 + j]; \
            split8(a, ah, al); \
            ACC = MFMA(ah, bh, ACC, 0,0,0); \
            ACC = MFMA(al, bh, ACC, 0,0,0); \
            ACC = MFMA(ah, bl, ACC, 0,0,0); }
        #define T0KT(KT) { bf16x8 bh, bl; \
            if (q == 3) { bh = *(const bf16x8*)(whibase + KT * 512); bl = wl##KT; } \
            else { float v[8]; \
              _Pragma("unroll") for (int j = 0; j < 8; ++j) \
                  v[j] = ub[(size_t)(kg0 + KT * 32 + lhi * 8 + j) * THREE_D]; \
              split8(v, bh, bl); } \
            T0M(acc0,  0, KT) T0M(acc1, 16, KT) T0M(acc2, 32, KT) T0M(acc3, 48, KT) }
        T0KT(0) T0KT(1) T0KT(2) T0KT(3) T0KT(4) T0KT(5) T0KT(6) T0KT(7)
        T0KT(8) T0KT(9) T0KT(10) T0KT(11) T0KT(12) T0KT(13) T0KT(14) T0KT(15)
        #undef T0KT
        #undef T0M
    }
    {
        unsigned int* dhi = (unsigned int*)hb;              // buf0 hi
        unsigned int* dlo = dhi + 131072;                   // buf0 lo
        EPILOGUE(0, dhi, dlo)
    }
    BARRIER(0)

    // ---- t = 1 .. 127 ----
    const int aidx = ((rt * 64 + llow) * DDIM + kbase * 32 + lhi * 8) >> 2;  // u64 idx
    for (int t = 1; t < TSTEPS; ++t) {
        const unsigned long long* shq =
            (const unsigned long long*)(hb + (size_t)((t - 1) & 1) * 524288);
        const unsigned long long* slq = shq + 65536;
        unsigned int* dhi = (unsigned int*)(hb + (size_t)(t & 1) * 524288);
        unsigned int* dlo = dhi + 131072;

        acc0 = f32x4{0.f,0.f,0.f,0.f}; acc1 = acc0; acc2 = acc0; acc3 = acc0;
        #define SM(ACC, ROFF, KT) { frag_u fh_, fl_; \
            fh_.d[0] = ALOAD(shq + aidx + (ROFF) * 256 + (KT) * 8); \
            fh_.d[1] = ALOAD(shq + aidx + (ROFF) * 256 + (KT) * 8 + 1); \
            fl_.d[0] = ALOAD(slq + aidx + (ROFF) * 256 + (KT) * 8); \
            fl_.d[1] = ALOAD(slq + aidx + (ROFF) * 256 + (KT) * 8 + 1); \
            ACC = MFMA(fh_.v, bh, ACC, 0,0,0); \
            ACC = MFMA(fl_.v, bh, ACC, 0,0,0); \
            ACC = MFMA(fh_.v, bl, ACC, 0,0,0); }
        #define SKT(KT) { \
            bf16x8 bh = *(const bf16x8*)(whibase + KT * 512); \
            bf16x8 bl = wl##KT; \
            SM(acc0, 0, KT) SM(acc1, 16, KT) SM(acc2, 32, KT) SM(acc3, 48, KT) }
        SKT(0) SKT(1) SKT(2) SKT(3) SKT(4) SKT(5) SKT(6) SKT(7)
        SKT(8) SKT(9) SKT(10) SKT(11) SKT(12) SKT(13) SKT(14) SKT(15)
        #undef SKT
        #undef SM
        EPILOGUE(t, dhi, dlo)
        if (t < TSTEPS - 1) BARRIER(t)
    }
}

extern "C" void kernel_launch(void* const* d_in, const int* in_sizes, int n_in,
                              void* d_out, int out_size, void* d_ws, size_t ws_size,
                              hipStream_t stream) {
    const float* x = (const float*)d_in[0];
    const float* W = (const float*)d_in[1];
    const float* U = (const float*)d_in[2];
    const float* b = (const float*)d_in[3];
    float* out = (float*)d_out;

    // ws: 2 MB state (2 bufs x [hi 512KB | lo 512KB]) + 32 KB sync counters
    unsigned short* hb = (unsigned short*)d_ws;
    int* syncc = (int*)((char*)d_ws + (2u << 20));

    hipMemsetAsync(syncc, 0, 8192 * sizeof(int), stream);

    void* kargs[] = { (void*)&x, (void*)&W, (void*)&U, (void*)&b,
                      (void*)&out, (void*)&hb, (void*)&syncc };
    // 148480 B dynamic LDS: 128 KB weights-hi + 17408 B padded gate buf
    hipLaunchCooperativeKernel((const void*)gru_persistent, dim3(256), dim3(512),
                               kargs, 148480, stream);
}

// Round 5
// 5136.374 us; speedup vs baseline: 2.5345x; 1.5165x over previous
//
#include <hip/hip_runtime.h>
#include <stdint.h>

// Autoregressive GRU  B=256, D=1024, T=128  — persistent cooperative kernel, v4b.
// (Resubmission of v4: round-4 bench died at container level with no counters
// and no fail flag; sync structure is identical to v3 which passed, and the
// added acquire fence is a non-waiting local cache op -> infra flake suspected.)
//
// v3 post-mortem: 61 us/step with MfmaUtil 4%, VALUBusy 2%, HBM 1.4% ->
// latency-serialized. 256 relaxed atomic u64 loads/wave/step x ~600cy == 150k
// cy == 61 us: the backend does NOT pipeline atomic loads (issue->wait->use).
// v4: plain pipelined bf16x8 A-loads + per-step ACQUIRE-ONLY fence:
//  - A-loads: *(const bf16x8*) (compiler prefetches under vmcnt; L2-cached).
//  - After each barrier: __builtin_amdgcn_fence(ACQUIRE, "agent") = cache
//    invalidate WITHOUT the buffer_wbl2 writeback that killed v2.
//  - All loop global stores are WRITE-THROUGH relaxed agent atomics (state u32,
//    out packed u64) -> L2 never dirty -> invalidate drops nothing.
//  - Unchanged from v3 (proven): wave=(q,kh) map, weights hi in LDS (128KB) +
//    lo in 16 named bf16x8/wave, padded gbuf, per-rt 64-block barrier,
//    3-term split-bf16 MFMA, t=0 = [x@Uz | x@Ur | 0 | x@Uh].

#define DDIM    1024
#define THREE_D 3072
#define TSTEPS  128

typedef short bf16x8 __attribute__((ext_vector_type(8)));
typedef float f32x4  __attribute__((ext_vector_type(4)));

static __device__ __forceinline__ unsigned short f2bf(float f) {
    union { float f; uint32_t u; } v; v.f = f;
    uint32_t u = v.u;
    uint32_t r = u + 0x7FFFu + ((u >> 16) & 1u);   // round-to-nearest-even
    return (unsigned short)(r >> 16);
}
static __device__ __forceinline__ float bf2f(unsigned short h) {
    union { uint32_t u; float f; } v; v.u = ((uint32_t)h) << 16; return v.f;
}
static __device__ __forceinline__ void split8(const float* v, bf16x8& hi, bf16x8& lo) {
    #pragma unroll
    for (int j = 0; j < 8; ++j) {
        unsigned short h = f2bf(v[j]);
        hi[j] = (short)h;
        lo[j] = (short)f2bf(v[j] - bf2f(h));
    }
}

#define MFMA __builtin_amdgcn_mfma_f32_16x16x32_bf16
#define ASTORE(P,V) __hip_atomic_store((P), (V), __ATOMIC_RELAXED, __HIP_MEMORY_SCOPE_AGENT)

__global__ __launch_bounds__(512, 2) void gru_persistent(
    const float* __restrict__ x, const float* __restrict__ W,
    const float* __restrict__ U, const float* __restrict__ bias,
    float* __restrict__ out, unsigned short* __restrict__ hb,
    int* __restrict__ syncc)
{
    extern __shared__ char smem[];
    unsigned short* whi = (unsigned short*)smem;   // [4][32][64][8] shorts = 128 KB
    float* gbuf = (float*)(smem + 131072);         // [4][64][17] f32 = 17408 B

    const int tid  = threadIdx.x;
    const int lane = tid & 63;
    const int wid  = tid >> 6;          // 0..7
    const int q    = wid >> 1;          // gate quarter (z | r | Wh | Uh)
    const int kh   = wid & 1;           // k-half
    const int dt   = blockIdx.x & 63;   // dim tile (16 dims)
    const int rt   = blockIdx.x >> 6;   // row tile (64 rows)
    const int llow = lane & 15;
    const int lhi  = lane >> 4;
    const int d    = dt * 16 + llow;    // B-frag column (dim within gate)
    const int kbase = kh * 16;          // first k-tile of this wave

    unsigned short* whibase = whi + (((q * 32 + kbase) * 64 + lane) << 3);

    // ---- one-time fold: M = [Wz+Uz | Wr+Ur | Wh | Uh]; hi -> LDS, lo -> regs
    bf16x8 wl0,wl1,wl2,wl3,wl4,wl5,wl6,wl7,wl8,wl9,wl10,wl11,wl12,wl13,wl14,wl15;
    {
        const int cc = (q == 0) ? d : (q == 1) ? (1024 + d) : (2048 + d);
        const float* m1 = (q == 3) ? U : W;
        const int k0 = kbase * 32 + lhi * 8;
        #define FOLD(KT) { float v[8]; bf16x8 bh_; \
            _Pragma("unroll") for (int j = 0; j < 8; ++j) { \
                int k = k0 + KT * 32 + j; \
                float val = m1[(size_t)k * THREE_D + cc]; \
                if (q <= 1) val += U[(size_t)k * THREE_D + cc]; \
                v[j] = val; } \
            split8(v, bh_, wl##KT); \
            *(bf16x8*)(whibase + KT * 512) = bh_; }
        FOLD(0) FOLD(1) FOLD(2) FOLD(3) FOLD(4) FOLD(5) FOLD(6) FOLD(7)
        FOLD(8) FOLD(9) FOLD(10) FOLD(11) FOLD(12) FOLD(13) FOLD(14) FOLD(15)
        #undef FOLD
    }

    // ---- epilogue constants: thread owns 1 row x 2 adjacent cols ----
    const int erow = tid >> 3;          // 0..63
    const int ec   = (tid & 7) * 2;     // 0,2,...,14
    const int dd   = dt * 16 + ec;
    const float bz0 = bias[dd],        bz1 = bias[dd + 1];
    const float br0 = bias[1024 + dd], br1 = bias[1025 + dd];
    const float bx0 = bias[2048 + dd], bx1 = bias[2049 + dd];
    const int grow = rt * 64 + erow;
    const size_t obase = (size_t)grow * (TSTEPS * DDIM) + dd;
    const int sidx  = (grow * DDIM + dd) >> 1;     // u32 index into state
    float hp0 = x[(size_t)grow * DDIM + dd];
    float hp1 = x[(size_t)grow * DDIM + dd + 1];

    f32x4 acc0 = {0.f,0.f,0.f,0.f}, acc1 = acc0, acc2 = acc0, acc3 = acc0;

    // MFMA C/D: col = lane&15, row = (lane>>4)*4 + reg  [measured m89]
    #define GW(ACC, M) { _Pragma("unroll") for (int r = 0; r < 4; ++r) \
        gbuf[(q * 64 + (M) * 16 + lhi * 4 + r) * 17 + llow] = (ACC)[r]; }
    #define GA(ACC, M) { _Pragma("unroll") for (int r = 0; r < 4; ++r) \
        gbuf[(q * 64 + (M) * 16 + lhi * 4 + r) * 17 + llow] += (ACC)[r]; }
    #define EPILOGUE(T, DHI, DLO) { \
        if (kh == 0) { GW(acc0,0) GW(acc1,1) GW(acc2,2) GW(acc3,3) } \
        __syncthreads(); \
        if (kh == 1) { GA(acc0,0) GA(acc1,1) GA(acc2,2) GA(acc3,3) } \
        __syncthreads(); \
        float gz0 = gbuf[(0*64 + erow)*17 + ec]     + bz0; \
        float gz1 = gbuf[(0*64 + erow)*17 + ec + 1] + bz1; \
        float gr0 = gbuf[(1*64 + erow)*17 + ec]     + br0; \
        float gr1 = gbuf[(1*64 + erow)*17 + ec + 1] + br1; \
        float gx0 = gbuf[(2*64 + erow)*17 + ec]     + bx0; \
        float gx1 = gbuf[(2*64 + erow)*17 + ec + 1] + bx1; \
        float gu0 = gbuf[(3*64 + erow)*17 + ec]; \
        float gu1 = gbuf[(3*64 + erow)*17 + ec + 1]; \
        float z0 = 1.f/(1.f+__expf(-gz0)), z1 = 1.f/(1.f+__expf(-gz1)); \
        float r0 = 1.f/(1.f+__expf(-gr0)), r1 = 1.f/(1.f+__expf(-gr1)); \
        float hh0 = tanhf(gx0 + r0*gu0), hh1 = tanhf(gx1 + r1*gu1); \
        float hn0 = z0*hp0 + (1.f-z0)*hh0, hn1 = z1*hp1 + (1.f-z1)*hh1; \
        hp0 = hn0; hp1 = hn1; \
        { union { float f[2]; unsigned long long u; } op_; \
          op_.f[0] = hn0; op_.f[1] = hn1; \
          ASTORE((unsigned long long*)(out + obase + (size_t)(T)*DDIM), op_.u); } \
        unsigned short h0_ = f2bf(hn0), h1_ = f2bf(hn1); \
        unsigned int hw_ = (unsigned int)h0_ | ((unsigned int)h1_ << 16); \
        unsigned int lw_ = (unsigned int)f2bf(hn0 - bf2f(h0_)) \
                         | ((unsigned int)f2bf(hn1 - bf2f(h1_)) << 16); \
        ASTORE((DHI) + sidx, hw_); \
        ASTORE((DLO) + sidx, lw_); }

    // per-rt-group 64-block barrier. All loop stores are write-through atomics
    // (L2 never dirty), so the exit fence is ACQUIRE-ONLY (inv, no writeback).
    #define BARRIER(T) { \
        asm volatile("s_waitcnt vmcnt(0)" ::: "memory"); \
        __syncthreads(); \
        if (tid == 0) { \
            int* c = syncc + ((T) * 4 + rt) * 16; \
            __hip_atomic_fetch_add(c, 1, __ATOMIC_RELAXED, __HIP_MEMORY_SCOPE_AGENT); \
            while (__hip_atomic_load(c, __ATOMIC_RELAXED, __HIP_MEMORY_SCOPE_AGENT) < 64) \
                __builtin_amdgcn_s_sleep(2); \
        } \
        __syncthreads(); \
        __builtin_amdgcn_fence(__ATOMIC_ACQUIRE, "agent"); }

    __syncthreads();

    // ---- t = 0:  gates = [x@Uz | x@Ur | 0 | x@Uh], A = split(x) ----
    if (q != 2) {
        const float* xb = x + (size_t)(rt * 64 + llow) * DDIM + lhi * 8;
        const int cc = (q == 0) ? d : (q == 1) ? (1024 + d) : (2048 + d);
        const float* ub = U + cc;
        const int kg0 = kbase * 32;
        #define T0M(ACC, ROFF, KT) { float a[8]; bf16x8 ah, al; \
            _Pragma("unroll") for (int j = 0; j < 8; ++j) \
                a[j] = xb[(ROFF) * DDIM + kg0 + (KT) * 32 + j]; \
            split8(a, ah, al); \
            ACC = MFMA(ah, bh, ACC, 0,0,0); \
            ACC = MFMA(al, bh, ACC, 0,0,0); \
            ACC = MFMA(ah, bl, ACC, 0,0,0); }
        #define T0KT(KT) { bf16x8 bh, bl; \
            if (q == 3) { bh = *(const bf16x8*)(whibase + KT * 512); bl = wl##KT; } \
            else { float v[8]; \
              _Pragma("unroll") for (int j = 0; j < 8; ++j) \
                  v[j] = ub[(size_t)(kg0 + KT * 32 + lhi * 8 + j) * THREE_D]; \
              split8(v, bh, bl); } \
            T0M(acc0,  0, KT) T0M(acc1, 16, KT) T0M(acc2, 32, KT) T0M(acc3, 48, KT) }
        T0KT(0) T0KT(1) T0KT(2) T0KT(3) T0KT(4) T0KT(5) T0KT(6) T0KT(7)
        T0KT(8) T0KT(9) T0KT(10) T0KT(11) T0KT(12) T0KT(13) T0KT(14) T0KT(15)
        #undef T0KT
        #undef T0M
    }
    {
        unsigned int* dhi = (unsigned int*)hb;              // buf0 hi
        unsigned int* dlo = dhi + 131072;                   // buf0 lo
        EPILOGUE(0, dhi, dlo)
    }
    BARRIER(0)

    // ---- t = 1 .. 127: plain pipelined A-loads (caches fresh post-fence) ----
    for (int t = 1; t < TSTEPS; ++t) {
        const unsigned short* sh = hb + (size_t)((t - 1) & 1) * 524288;
        const unsigned short* sl = sh + 262144;
        unsigned int* dhi = (unsigned int*)(hb + (size_t)(t & 1) * 524288);
        unsigned int* dlo = dhi + 131072;
        const unsigned short* ahp = sh + (size_t)(rt * 64 + llow) * DDIM + lhi * 8 + kbase * 32;
        const unsigned short* alp = sl + (size_t)(rt * 64 + llow) * DDIM + lhi * 8 + kbase * 32;

        acc0 = f32x4{0.f,0.f,0.f,0.f}; acc1 = acc0; acc2 = acc0; acc3 = acc0;
        #define SM(ACC, ROFF, KT) { \
            bf16x8 ah = *(const bf16x8*)(ahp + (ROFF) * DDIM + (KT) * 32); \
            bf16x8 al = *(const bf16x8*)(alp + (ROFF) * DDIM + (KT) * 32); \
            ACC = MFMA(ah, bh, ACC, 0,0,0); \
            ACC = MFMA(al, bh, ACC, 0,0,0); \
            ACC = MFMA(ah, bl, ACC, 0,0,0); }
        #define SKT(KT) { \
            bf16x8 bh = *(const bf16x8*)(whibase + KT * 512); \
            bf16x8 bl = wl##KT; \
            SM(acc0, 0, KT) SM(acc1, 16, KT) SM(acc2, 32, KT) SM(acc3, 48, KT) }
        SKT(0) SKT(1) SKT(2) SKT(3) SKT(4) SKT(5) SKT(6) SKT(7)
        SKT(8) SKT(9) SKT(10) SKT(11) SKT(12) SKT(13) SKT(14) SKT(15)
        #undef SKT
        #undef SM
        EPILOGUE(t, dhi, dlo)
        if (t < TSTEPS - 1) BARRIER(t)
    }
}

extern "C" void kernel_launch(void* const* d_in, const int* in_sizes, int n_in,
                              void* d_out, int out_size, void* d_ws, size_t ws_size,
                              hipStream_t stream) {
    const float* x = (const float*)d_in[0];
    const float* W = (const float*)d_in[1];
    const float* U = (const float*)d_in[2];
    const float* b = (const float*)d_in[3];
    float* out = (float*)d_out;

    // ws: 2 MB state (2 bufs x [hi 512KB | lo 512KB]) + 32 KB sync counters
    unsigned short* hb = (unsigned short*)d_ws;
    int* syncc = (int*)((char*)d_ws + (2u << 20));

    hipMemsetAsync(syncc, 0, 8192 * sizeof(int), stream);

    void* kargs[] = { (void*)&x, (void*)&W, (void*)&U, (void*)&b,
                      (void*)&out, (void*)&hb, (void*)&syncc };
    // 148480 B dynamic LDS: 128 KB weights-hi + 17408 B padded gate buf
    hipLaunchCooperativeKernel((const void*)gru_persistent, dim3(256), dim3(512),
                               kargs, 148480, stream);
}

// Round 6
// 4359.460 us; speedup vs baseline: 2.9861x; 1.1782x over previous
//
#include <hip/hip_runtime.h>
#include <stdint.h>

// Autoregressive GRU  B=256, D=1024, T=128  — persistent cooperative kernel, v5.
// v4b post-mortem: 40 us/step, all pipes idle, VGPR=128 -> no register headroom
// for load batching; 128 A-loads/wave/step (4x gate redundancy) each pay
// exposed L2/MALL latency. v5 restructure:
//  - wave = (gate-pair gg, k-quarter kq): gg=0 -> {gz,gr}, gg=1 -> {gx,gu};
//    each wave owns 256 K. A-loads/wave: 128 -> 64 (redundancy 4x -> 2x).
//  - Weights FULLY register-resident: 32 named bf16x8/wave (128 VGPR), no LDS
//    weights (each fragment used by exactly one wave). acc = 8 named f32x4.
//  - LDS = only k-partial reduction buf gbuf[4][4][64][20] (80 KB, stride-20
//    padding -> <=2-way bank aliasing; v4b had 16.8M conflicts on stride-16/17).
//  - Unchanged (proven v4b): write-through relaxed agent-atomic stores (state
//    u32, out u64), acquire-only agent fence per step, per-rt 64-block counter
//    barrier, 3-term split-bf16 MFMA, f32 h_prev in regs,
//    t=0 gates = [x@Uz | x@Ur | 0 | x@Uh] (g3's resident weights ARE Uh).

#define DDIM    1024
#define THREE_D 3072
#define TSTEPS  128

typedef short bf16x8 __attribute__((ext_vector_type(8)));
typedef float f32x4  __attribute__((ext_vector_type(4)));

static __device__ __forceinline__ unsigned short f2bf(float f) {
    union { float f; uint32_t u; } v; v.f = f;
    uint32_t u = v.u;
    uint32_t r = u + 0x7FFFu + ((u >> 16) & 1u);   // round-to-nearest-even
    return (unsigned short)(r >> 16);
}
static __device__ __forceinline__ float bf2f(unsigned short h) {
    union { uint32_t u; float f; } v; v.u = ((uint32_t)h) << 16; return v.f;
}
static __device__ __forceinline__ void split8(const float* v, bf16x8& hi, bf16x8& lo) {
    #pragma unroll
    for (int j = 0; j < 8; ++j) {
        unsigned short h = f2bf(v[j]);
        hi[j] = (short)h;
        lo[j] = (short)f2bf(v[j] - bf2f(h));
    }
}

#define MFMA3(ACC, A, B) ACC = __builtin_amdgcn_mfma_f32_16x16x32_bf16((A), (B), (ACC), 0, 0, 0);
#define ASTORE(P,V) __hip_atomic_store((P), (V), __ATOMIC_RELAXED, __HIP_MEMORY_SCOPE_AGENT)

// gbuf float index: [kq][gate][row][col], col-stride 20 (bank spread)
#define GIDX(KQ,G,R,C) ((((KQ)*4 + (G))*64 + (R))*20 + (C))

__global__ __launch_bounds__(512, 2) void gru_persistent(
    const float* __restrict__ x, const float* __restrict__ W,
    const float* __restrict__ U, const float* __restrict__ bias,
    float* __restrict__ out, unsigned short* __restrict__ hb,
    int* __restrict__ syncc)
{
    extern __shared__ char smem[];
    float* gbuf = (float*)smem;          // 4*4*64*20*4 = 81920 B

    const int tid  = threadIdx.x;
    const int lane = tid & 63;
    const int wid  = tid >> 6;          // 0..7
    const int gg   = wid >> 2;          // gate-pair: 0 -> {gz,gr}, 1 -> {gx,gu}
    const int kq   = wid & 3;           // k-quarter (256 K values)
    const int dt   = blockIdx.x & 63;   // dim tile (16 dims)
    const int rt   = blockIdx.x >> 6;   // row tile (64 rows)
    const int llow = lane & 15;
    const int lhi  = lane >> 4;
    const int d    = dt * 16 + llow;    // B-frag column (dim within gate)
    const int kq0  = kq * 256;

    // ---- one-time fold, ALL weights in named registers ----
    // gate A: gg==0 -> gz = Wz+Uz ; gg==1 -> gx = Wh
    // gate B: gg==0 -> gr = Wr+Ur ; gg==1 -> gu = Uh
    bf16x8 whA0,whA1,whA2,whA3,whA4,whA5,whA6,whA7;
    bf16x8 wlA0,wlA1,wlA2,wlA3,wlA4,wlA5,wlA6,wlA7;
    bf16x8 whB0,whB1,whB2,whB3,whB4,whB5,whB6,whB7;
    bf16x8 wlB0,wlB1,wlB2,wlB3,wlB4,wlB5,wlB6,wlB7;
    {
        const float* pA = W;
        const int   ccA = gg ? (2048 + d) : d;
        const float* pB = gg ? U : W;
        const int   ccB = gg ? (2048 + d) : (1024 + d);
        const int  addu = (gg == 0);
        const int    k0 = kq0 + lhi * 8;
        #define FOLD(KT) { float va[8], vb[8]; \
            _Pragma("unroll") for (int j = 0; j < 8; ++j) { \
                size_t kr = (size_t)(k0 + (KT) * 32 + j) * THREE_D; \
                float a_ = pA[kr + ccA], b_ = pB[kr + ccB]; \
                if (addu) { a_ += U[kr + ccA]; b_ += U[kr + ccB]; } \
                va[j] = a_; vb[j] = b_; } \
            split8(va, whA##KT, wlA##KT); split8(vb, whB##KT, wlB##KT); }
        FOLD(0) FOLD(1) FOLD(2) FOLD(3) FOLD(4) FOLD(5) FOLD(6) FOLD(7)
        #undef FOLD
    }

    // ---- epilogue constants: thread owns 1 row x 2 adjacent cols ----
    const int erow = tid >> 3;          // 0..63
    const int ec   = (tid & 7) * 2;     // 0,2,...,14
    const int dd   = dt * 16 + ec;
    const float bz0 = bias[dd],        bz1 = bias[dd + 1];
    const float br0 = bias[1024 + dd], br1 = bias[1025 + dd];
    const float bx0 = bias[2048 + dd], bx1 = bias[2049 + dd];
    const int grow = rt * 64 + erow;
    const size_t obase = (size_t)grow * (TSTEPS * DDIM) + dd;
    const int sidx  = (grow * DDIM + dd) >> 1;     // u32 index into state
    float hp0 = x[(size_t)grow * DDIM + dd];
    float hp1 = x[(size_t)grow * DDIM + dd + 1];

    f32x4 aA0 = {0.f,0.f,0.f,0.f}, aA1 = aA0, aA2 = aA0, aA3 = aA0;
    f32x4 aB0 = aA0, aB1 = aA0, aB2 = aA0, aB3 = aA0;

    // MFMA C/D: col = lane&15, row = (lane>>4)*4 + reg  [measured m89]
    #define GWRITE { const int gA_ = gg * 2, gB_ = gg * 2 + 1; \
        _Pragma("unroll") for (int r = 0; r < 4; ++r) { \
            gbuf[GIDX(kq, gA_,  0 + lhi * 4 + r, llow)] = aA0[r]; \
            gbuf[GIDX(kq, gA_, 16 + lhi * 4 + r, llow)] = aA1[r]; \
            gbuf[GIDX(kq, gA_, 32 + lhi * 4 + r, llow)] = aA2[r]; \
            gbuf[GIDX(kq, gA_, 48 + lhi * 4 + r, llow)] = aA3[r]; \
            gbuf[GIDX(kq, gB_,  0 + lhi * 4 + r, llow)] = aB0[r]; \
            gbuf[GIDX(kq, gB_, 16 + lhi * 4 + r, llow)] = aB1[r]; \
            gbuf[GIDX(kq, gB_, 32 + lhi * 4 + r, llow)] = aB2[r]; \
            gbuf[GIDX(kq, gB_, 48 + lhi * 4 + r, llow)] = aB3[r]; } }

    #define SUM4(G,C) (gbuf[GIDX(0,G,erow,C)] + gbuf[GIDX(1,G,erow,C)] \
                     + gbuf[GIDX(2,G,erow,C)] + gbuf[GIDX(3,G,erow,C)])

    #define EPILOGUE(T, DHI, DLO) { \
        GWRITE \
        __syncthreads(); \
        float gz0 = SUM4(0, ec) + bz0, gz1 = SUM4(0, ec + 1) + bz1; \
        float gr0 = SUM4(1, ec) + br0, gr1 = SUM4(1, ec + 1) + br1; \
        float gx0 = SUM4(2, ec) + bx0, gx1 = SUM4(2, ec + 1) + bx1; \
        float gu0 = SUM4(3, ec),       gu1 = SUM4(3, ec + 1); \
        float z0 = 1.f/(1.f+__expf(-gz0)), z1 = 1.f/(1.f+__expf(-gz1)); \
        float r0 = 1.f/(1.f+__expf(-gr0)), r1 = 1.f/(1.f+__expf(-gr1)); \
        float hh0 = tanhf(gx0 + r0*gu0), hh1 = tanhf(gx1 + r1*gu1); \
        float hn0 = z0*hp0 + (1.f-z0)*hh0, hn1 = z1*hp1 + (1.f-z1)*hh1; \
        hp0 = hn0; hp1 = hn1; \
        { union { float f[2]; unsigned long long u; } op_; \
          op_.f[0] = hn0; op_.f[1] = hn1; \
          ASTORE((unsigned long long*)(out + obase + (size_t)(T)*DDIM), op_.u); } \
        unsigned short h0_ = f2bf(hn0), h1_ = f2bf(hn1); \
        unsigned int hw_ = (unsigned int)h0_ | ((unsigned int)h1_ << 16); \
        unsigned int lw_ = (unsigned int)f2bf(hn0 - bf2f(h0_)) \
                         | ((unsigned int)f2bf(hn1 - bf2f(h1_)) << 16); \
        ASTORE((DHI) + sidx, hw_); \
        ASTORE((DLO) + sidx, lw_); }

    // per-rt-group 64-block barrier; acquire-only fence (stores write-through)
    #define BARRIER(T) { \
        asm volatile("s_waitcnt vmcnt(0)" ::: "memory"); \
        __syncthreads(); \
        if (tid == 0) { \
            int* c = syncc + ((T) * 4 + rt) * 16; \
            __hip_atomic_fetch_add(c, 1, __ATOMIC_RELAXED, __HIP_MEMORY_SCOPE_AGENT); \
            while (__hip_atomic_load(c, __ATOMIC_RELAXED, __HIP_MEMORY_SCOPE_AGENT) < 64) \
                __builtin_amdgcn_s_sleep(2); \
        } \
        __syncthreads(); \
        __builtin_amdgcn_fence(__ATOMIC_ACQUIRE, "agent"); }

    __syncthreads();

    // ---- t = 0: gates = [x@Uz | x@Ur | 0 | x@Uh]; A = split(x) ----
    {
        const float* xb = x + (size_t)(rt * 64 + llow) * DDIM + lhi * 8;
        if (gg == 0) {
            const float* uz = U + d;
            const float* ur = U + 1024 + d;
            #define T0M(AZ, AR, ROFF, KT) { float a[8]; bf16x8 ah, al; \
                _Pragma("unroll") for (int j = 0; j < 8; ++j) \
                    a[j] = xb[(ROFF) * DDIM + kq0 + (KT) * 32 + j]; \
                split8(a, ah, al); \
                MFMA3(AZ, ah, bhz) MFMA3(AZ, al, bhz) MFMA3(AZ, ah, blz) \
                MFMA3(AR, ah, bhr) MFMA3(AR, al, bhr) MFMA3(AR, ah, blr) }
            #define T0KT(KT) { bf16x8 bhz, blz, bhr, blr; \
                { float vz[8], vr[8]; \
                  _Pragma("unroll") for (int j = 0; j < 8; ++j) { \
                      size_t kr = (size_t)(kq0 + (KT) * 32 + lhi * 8 + j) * THREE_D; \
                      vz[j] = uz[kr]; vr[j] = ur[kr]; } \
                  split8(vz, bhz, blz); split8(vr, bhr, blr); } \
                T0M(aA0, aB0,  0, KT) T0M(aA1, aB1, 16, KT) \
                T0M(aA2, aB2, 32, KT) T0M(aA3, aB3, 48, KT) }
            T0KT(0) T0KT(1) T0KT(2) T0KT(3) T0KT(4) T0KT(5) T0KT(6) T0KT(7)
            #undef T0KT
            #undef T0M
        } else {
            // g2 (gx): zero; g3 (gu): resident whB/wlB == Uh
            #define T0MB(AB, ROFF, KT) { float a[8]; bf16x8 ah, al; \
                _Pragma("unroll") for (int j = 0; j < 8; ++j) \
                    a[j] = xb[(ROFF) * DDIM + kq0 + (KT) * 32 + j]; \
                split8(a, ah, al); \
                MFMA3(AB, ah, whB##KT) MFMA3(AB, al, whB##KT) MFMA3(AB, ah, wlB##KT) }
            #define T0KB(KT) { T0MB(aB0,  0, KT) T0MB(aB1, 16, KT) \
                                T0MB(aB2, 32, KT) T0MB(aB3, 48, KT) }
            T0KB(0) T0KB(1) T0KB(2) T0KB(3) T0KB(4) T0KB(5) T0KB(6) T0KB(7)
            #undef T0KB
            #undef T0MB
        }
        unsigned int* dhi = (unsigned int*)hb;              // buf0 hi
        unsigned int* dlo = dhi + 131072;                   // buf0 lo
        EPILOGUE(0, dhi, dlo)
    }
    BARRIER(0)

    // ---- t = 1 .. 127: A plain pipelined loads; B all in registers ----
    for (int t = 1; t < TSTEPS; ++t) {
        const unsigned short* sh = hb + (size_t)((t - 1) & 1) * 524288;
        const unsigned short* sl = sh + 262144;
        unsigned int* dhi = (unsigned int*)(hb + (size_t)(t & 1) * 524288);
        unsigned int* dlo = dhi + 131072;
        const unsigned short* ahp = sh + (size_t)(rt * 64 + llow) * DDIM + kq0 + lhi * 8;
        const unsigned short* alp = sl + (size_t)(rt * 64 + llow) * DDIM + kq0 + lhi * 8;

        aA0 = f32x4{0.f,0.f,0.f,0.f}; aA1 = aA0; aA2 = aA0; aA3 = aA0;
        aB0 = aA0; aB1 = aA0; aB2 = aA0; aB3 = aA0;

        #define SKT(KT) { \
            bf16x8 h0 = *(const bf16x8*)(ahp + (KT) * 32); \
            bf16x8 h1 = *(const bf16x8*)(ahp + 16 * DDIM + (KT) * 32); \
            bf16x8 h2 = *(const bf16x8*)(ahp + 32 * DDIM + (KT) * 32); \
            bf16x8 h3 = *(const bf16x8*)(ahp + 48 * DDIM + (KT) * 32); \
            bf16x8 l0 = *(const bf16x8*)(alp + (KT) * 32); \
            bf16x8 l1 = *(const bf16x8*)(alp + 16 * DDIM + (KT) * 32); \
            bf16x8 l2 = *(const bf16x8*)(alp + 32 * DDIM + (KT) * 32); \
            bf16x8 l3 = *(const bf16x8*)(alp + 48 * DDIM + (KT) * 32); \
            MFMA3(aA0, h0, whA##KT) MFMA3(aA0, l0, whA##KT) MFMA3(aA0, h0, wlA##KT) \
            MFMA3(aB0, h0, whB##KT) MFMA3(aB0, l0, whB##KT) MFMA3(aB0, h0, wlB##KT) \
            MFMA3(aA1, h1, whA##KT) MFMA3(aA1, l1, whA##KT) MFMA3(aA1, h1, wlA##KT) \
            MFMA3(aB1, h1, whB##KT) MFMA3(aB1, l1, whB##KT) MFMA3(aB1, h1, wlB##KT) \
            MFMA3(aA2, h2, whA##KT) MFMA3(aA2, l2, whA##KT) MFMA3(aA2, h2, wlA##KT) \
            MFMA3(aB2, h2, whB##KT) MFMA3(aB2, l2, whB##KT) MFMA3(aB2, h2, wlB##KT) \
            MFMA3(aA3, h3, whA##KT) MFMA3(aA3, l3, whA##KT) MFMA3(aA3, h3, wlA##KT) \
            MFMA3(aB3, h3, whB##KT) MFMA3(aB3, l3, whB##KT) MFMA3(aB3, h3, wlB##KT) }
        SKT(0) SKT(1) SKT(2) SKT(3) SKT(4) SKT(5) SKT(6) SKT(7)
        #undef SKT

        EPILOGUE(t, dhi, dlo)
        if (t < TSTEPS - 1) BARRIER(t)
    }
}

extern "C" void kernel_launch(void* const* d_in, const int* in_sizes, int n_in,
                              void* d_out, int out_size, void* d_ws, size_t ws_size,
                              hipStream_t stream) {
    const float* x = (const float*)d_in[0];
    const float* W = (const float*)d_in[1];
    const float* U = (const float*)d_in[2];
    const float* b = (const float*)d_in[3];
    float* out = (float*)d_out;

    // ws: 2 MB state (2 bufs x [hi 512KB | lo 512KB]) + 32 KB sync counters
    unsigned short* hb = (unsigned short*)d_ws;
    int* syncc = (int*)((char*)d_ws + (2u << 20));

    hipMemsetAsync(syncc, 0, 8192 * sizeof(int), stream);

    void* kargs[] = { (void*)&x, (void*)&W, (void*)&U, (void*)&b,
                      (void*)&out, (void*)&hb, (void*)&syncc };
    // dynamic LDS: 81920 B reduction buffer only (weights are in registers)
    hipLaunchCooperativeKernel((const void*)gru_persistent, dim3(256), dim3(512),
                               kargs, 81920, stream);
}